// Round 3
// baseline (93.569 us; speedup 1.0000x reference)
//
#include <hip/hip_runtime.h>

// InstanceSegmentationLoss: reduces to a 33x33 joint histogram of (pred_id, true_id)
// over 4.19M pixels, then O(33^2) IoU math.
//
//   inter[n][m] = J[n][m]          (n,m in 1..32)
//   psum[n]     = sum_t J[n][t]    (row sums incl. background col 0)
//   tsum[m]     = sum_p J[p][m]    (col sums incl. background row 0)
//   dummy       = (sum_p p*rowsum[p] + sum_t t*colsum[t]) / 1e12
//   loss        = dummy + sum_n (1 - max_m iou[n][m])
//
// NOTE: histogram lives in a module-scope __device__ array, NOT d_ws —
// if ws_size==0 the d_ws pointer may be null and writing it faults the GPU
// (suspected cause of the R1/R2 container aborts).

#define NIDS  33            // ids 0..32 (0 = background)
#define HSIZE (NIDS * NIDS) // 1089

__device__ unsigned g_hist[HSIZE];

__global__ void zero_hist() {
    int i = blockIdx.x * blockDim.x + threadIdx.x;
    if (i < HSIZE) g_hist[i] = 0u;
}

__device__ __forceinline__ int clamp_id(float v) {
    int i = (int)v;
    i = i < 0 ? 0 : i;
    return i > (NIDS - 1) ? (NIDS - 1) : i;
}

__global__ void hist_kernel(const float4* __restrict__ pred,
                            const float4* __restrict__ tmask, int n4) {
    __shared__ unsigned sh[HSIZE];
    for (int i = threadIdx.x; i < HSIZE; i += blockDim.x) sh[i] = 0u;
    __syncthreads();

    const int stride = gridDim.x * blockDim.x;
    for (int i = blockIdx.x * blockDim.x + threadIdx.x; i < n4; i += stride) {
        float4 p = pred[i];
        float4 t = tmask[i];
        int p0 = clamp_id(p.x), p1 = clamp_id(p.y);
        int p2 = clamp_id(p.z), p3 = clamp_id(p.w);
        int t0 = clamp_id(t.x), t1 = clamp_id(t.y);
        int t2 = clamp_id(t.z), t3 = clamp_id(t.w);
        atomicAdd(&sh[p0 * NIDS + t0], 1u);
        atomicAdd(&sh[p1 * NIDS + t1], 1u);
        atomicAdd(&sh[p2 * NIDS + t2], 1u);
        atomicAdd(&sh[p3 * NIDS + t3], 1u);
    }
    __syncthreads();

    for (int i = threadIdx.x; i < HSIZE; i += blockDim.x) {
        unsigned v = sh[i];
        if (v) atomicAdd(&g_hist[i], v);
    }
}

__global__ void finalize_kernel(float* __restrict__ out) {
    __shared__ float sh[HSIZE];
    __shared__ float rowsum[NIDS], colsum[NIDS];
    __shared__ float maxv[32];

    const int tid = threadIdx.x;  // blockDim.x == 256
    for (int i = tid; i < HSIZE; i += blockDim.x) sh[i] = (float)g_hist[i];
    __syncthreads();

    if (tid < NIDS) {
        float rs = 0.f, cs = 0.f;
        for (int j = 0; j < NIDS; ++j) {
            rs += sh[tid * NIDS + j];
            cs += sh[j * NIDS + tid];
        }
        rowsum[tid] = rs;
        colsum[tid] = cs;
    }
    __syncthreads();

    if (tid < 32) {
        const int n = tid + 1;        // pred instance 1..32
        float best = 0.f;
        const float rs = rowsum[n];
        for (int m = 1; m < NIDS; ++m) {
            float inter = sh[n * NIDS + m];
            float uni   = rs + colsum[m] - inter;
            float iou   = (uni > 0.f) ? (inter / uni) : 0.f;
            best = fmaxf(best, iou);
        }
        maxv[tid] = best;
    }
    __syncthreads();

    if (tid == 0) {
        double sp = 0.0, st = 0.0;
        for (int i = 1; i < NIDS; ++i) {
            sp += (double)i * (double)rowsum[i];
            st += (double)i * (double)colsum[i];
        }
        float loss = 0.f;
        for (int i = 0; i < 32; ++i) loss += 1.0f - maxv[i];
        out[0] = loss + (float)((sp + st) * 1e-12);
    }
}

extern "C" void kernel_launch(void* const* d_in, const int* in_sizes, int n_in,
                              void* d_out, int out_size, void* d_ws, size_t ws_size,
                              hipStream_t stream) {
    const float* pred  = (const float*)d_in[0];
    const float* tmask = (const float*)d_in[1];
    float* out = (float*)d_out;

    const int n  = in_sizes[0];  // 2048*2048 = 4194304, divisible by 4
    const int n4 = n / 4;

    zero_hist<<<(HSIZE + 255) / 256, 256, 0, stream>>>();
    hist_kernel<<<512, 256, 0, stream>>>((const float4*)pred, (const float4*)tmask, n4);
    finalize_kernel<<<1, 256, 0, stream>>>(out);
}